// Round 1
// baseline (849.563 us; speedup 1.0000x reference)
//
#include <hip/hip_runtime.h>
#include <hip/hip_bf16.h>

// Problem constants (B=2, L=2048, Dm=768, di=1536, ds=16, dc=4)
#define BB 2
#define LL 2048
#define DM 768
#define DI 1536
#define DS 16
#define MM (BB*LL)   // 4096 rows

typedef short bf16x8 __attribute__((ext_vector_type(8)));
typedef float f32x4  __attribute__((ext_vector_type(4)));

__device__ __forceinline__ void gl_lds16(const void* g, void* l) {
  __builtin_amdgcn_global_load_lds((const __attribute__((address_space(1))) void*)g,
                                   (__attribute__((address_space(3))) void*)l, 16, 0, 0);
}

// ---------------- fp32 -> bf16 convert (4 elems/thread) ----------------
struct bf4 { __hip_bfloat16 a, b, c, d; };
__global__ void cvt4_k(const float* __restrict__ in, __hip_bfloat16* __restrict__ out, int n4) {
  int i = blockIdx.x * 256 + threadIdx.x;
  if (i < n4) {
    float4 v = ((const float4*)in)[i];
    bf4 o = { __float2bfloat16(v.x), __float2bfloat16(v.y),
              __float2bfloat16(v.z), __float2bfloat16(v.w) };
    ((bf4*)out)[i] = o;
  }
}

// ---------------- NT bf16 MFMA GEMM: C[M,N] = A[M,K] * W[N,K]^T ----------------
// 64x64 tile / block of 256 threads (4 waves, 2x2), BK=32, single-buffered LDS.
// LDS staged frag-major via global_load_lds: frag idx == lane -> conflict-free b128 reads.
// EPI: 0 = plain fp32 store; 1 = +bias then softplus, fp32 store.
template<int EPI>
__global__ __launch_bounds__(256) void gemm_nt(const __hip_bfloat16* __restrict__ A,
                                               const __hip_bfloat16* __restrict__ W,
                                               float* __restrict__ C,
                                               const float* __restrict__ bias,
                                               int M, int N, int K) {
  __shared__ short sA[2048];   // 64 rows x 32 k bf16 (frag-major)
  __shared__ short sB[2048];
  const int t = threadIdx.x;
  const int m0 = blockIdx.y * 64, n0 = blockIdx.x * 64;
  const int w = t >> 6, lane = t & 63;
  const int wm = (w >> 1) * 32, wn = (w & 1) * 32;

  f32x4 acc[2][2] = {};

  // staging: row-in-tile = (t>>6)*16 + (t&15); k-chunk = ((t>>4)&3)*8
  const int srow  = ((t >> 6) << 4) | (t & 15);
  const int skoff = ((t >> 4) & 3) * 8;
  const __hip_bfloat16* gA = A + (size_t)(m0 + srow) * K + skoff;
  const __hip_bfloat16* gB = W + (size_t)(n0 + srow) * K + skoff;
  short* ldsAw = sA + (w << 9);   // wave-uniform LDS base (w*1024 bytes)
  short* ldsBw = sB + (w << 9);
  const bf16x8* fA = (const bf16x8*)sA;
  const bf16x8* fB = (const bf16x8*)sB;
  const int ga = wm >> 4, gb = wn >> 4;

  for (int k0 = 0; k0 < K; k0 += 32) {
    gl_lds16(gA + k0, ldsAw);
    gl_lds16(gB + k0, ldsBw);
    __syncthreads();
    bf16x8 a0 = fA[(ga + 0) * 64 + lane];
    bf16x8 a1 = fA[(ga + 1) * 64 + lane];
    bf16x8 b0 = fB[(gb + 0) * 64 + lane];
    bf16x8 b1 = fB[(gb + 1) * 64 + lane];
    acc[0][0] = __builtin_amdgcn_mfma_f32_16x16x32_bf16(a0, b0, acc[0][0], 0, 0, 0);
    acc[0][1] = __builtin_amdgcn_mfma_f32_16x16x32_bf16(a0, b1, acc[0][1], 0, 0, 0);
    acc[1][0] = __builtin_amdgcn_mfma_f32_16x16x32_bf16(a1, b0, acc[1][0], 0, 0, 0);
    acc[1][1] = __builtin_amdgcn_mfma_f32_16x16x32_bf16(a1, b1, acc[1][1], 0, 0, 0);
    __syncthreads();
  }

  const int q = lane >> 4, mm = lane & 15;
  #pragma unroll
  for (int i = 0; i < 2; i++)
    #pragma unroll
    for (int j = 0; j < 2; j++) {
      int r0  = m0 + wm + i * 16 + q * 4;
      int col = n0 + wn + j * 16 + mm;
      float bv = (EPI == 1) ? bias[col] : 0.f;
      #pragma unroll
      for (int r = 0; r < 4; r++) {
        float v = acc[i][j][r];
        if (EPI == 1) { v += bv; v = (v > 20.f) ? v : log1pf(__expf(v)); }
        C[(size_t)(r0 + r) * N + col] = v;
      }
    }
}

// ---------------- depthwise causal conv (dc=4) + SiLU; writes fp32 + bf16 ----------------
__global__ __launch_bounds__(256) void conv_silu_k(const float* __restrict__ xz,
                                                   const float* __restrict__ Wc,
                                                   float* __restrict__ xc,
                                                   __hip_bfloat16* __restrict__ xcbf) {
  int idx = blockIdx.x * 256 + threadIdx.x;
  if (idx >= MM * DI) return;
  int d = idx % DI;
  int r = idx / DI;
  int l = r & (LL - 1);
  float4 wv = ((const float4*)Wc)[d];  // W_conv[d, 0, 0..3]
  const float* xp = xz + (size_t)r * (2 * DI) + d;  // x_part half, row stride 3072
  float acc = wv.w * xp[0];
  if (l >= 1) acc += wv.z * xp[-(ptrdiff_t)(2 * DI)];
  if (l >= 2) acc += wv.y * xp[-(ptrdiff_t)(4 * DI)];
  if (l >= 3) acc += wv.x * xp[-(ptrdiff_t)(6 * DI)];
  float s = acc / (1.f + __expf(-acc));   // silu
  xc[idx] = s;
  xcbf[idx] = __float2bfloat16(s);
}

// ---------------- x_dbl = xc @ W_x.T  (N=32, K=1536), one row per block ----------------
__global__ __launch_bounds__(256) void xdbl_k(const float* __restrict__ xc,
                                              const float* __restrict__ Wx,
                                              float* __restrict__ xd) {
  __shared__ float row[DI];
  __shared__ float red[256];
  const int m = blockIdx.x, t = threadIdx.x;
  for (int i = t; i < DI; i += 256) row[i] = xc[(size_t)m * DI + i];
  __syncthreads();
  const int n = t & 31, rr = t >> 5;             // 32 outputs x 8 k-slices of 192
  const float4* w4 = (const float4*)(Wx + (size_t)n * DI + rr * 192);
  const float4* r4 = (const float4*)(row + rr * 192);
  float ss = 0.f;
  #pragma unroll 8
  for (int k = 0; k < 48; k++) {
    float4 a = r4[k], b = w4[k];
    ss += a.x * b.x + a.y * b.y + a.z * b.z + a.w * b.w;
  }
  red[t] = ss;
  __syncthreads();
  if (t < 32) {
    float tot = 0.f;
    #pragma unroll
    for (int r2 = 0; r2 < 8; r2++) tot += red[r2 * 32 + t];
    xd[(size_t)m * 32 + t] = tot;
  }
}

// ---------------- selective scan + (y + D*xc)*silu(z), bf16 out ----------------
// block = 256 threads = 16 channels x 16 states; grid = 2 batches * 96 channel-groups
__global__ __launch_bounds__(256) void scan_k(const float* __restrict__ delta,
                                              const float* __restrict__ xdbl,
                                              const float* __restrict__ A_log,
                                              const float* __restrict__ Dp,
                                              const float* __restrict__ xc,
                                              const float* __restrict__ xz,
                                              __hip_bfloat16* __restrict__ ypbf) {
  __shared__ float sD[64 * 16];
  __shared__ float sBC[64 * 32];
  __shared__ float sY[64 * 16];
  const int t = threadIdx.x;
  const int b = blockIdx.x / (DI / 16);
  const int ch0 = (blockIdx.x % (DI / 16)) * 16;
  const int s = t & 15, c = (t >> 4) & 15;
  const float aS = -__expf(A_log[s]);       // A[s] = -exp(A_log[s])
  const float Dv = Dp[ch0 + (t & 15)];      // used in post with dloc = t&15
  float h = 0.f;
  const float* dbase = delta + (size_t)b * LL * DI + ch0;
  const float* bcbase = xdbl + (size_t)b * LL * 32;

  for (int l0 = 0; l0 < LL; l0 += 64) {
    // stage delta tile (64 x 16) and B/C tile (64 x 32, contiguous)
    {
      int dloc = t & 15, i0 = t >> 4;
      #pragma unroll
      for (int rr = 0; rr < 4; rr++) {
        int i = i0 + rr * 16;
        sD[i * 16 + dloc] = dbase[(size_t)(l0 + i) * DI + dloc];
      }
      const float4* src = (const float4*)(bcbase + (size_t)l0 * 32);
      ((float4*)sBC)[t * 2]     = src[t * 2];
      ((float4*)sBC)[t * 2 + 1] = src[t * 2 + 1];
    }
    __syncthreads();

    #pragma unroll 4
    for (int i = 0; i < 64; i++) {
      float dlt = sD[i * 16 + c];
      float Bv  = sBC[i * 32 + s];
      float Cv  = sBC[i * 32 + 16 + s];
      float dA  = __expf(dlt * aS);
      h = dA * h + dlt * Bv;
      float p = h * Cv;
      p += __shfl_xor(p, 1);
      p += __shfl_xor(p, 2);
      p += __shfl_xor(p, 4);
      p += __shfl_xor(p, 8);
      if (s == 0) sY[i * 16 + c] = p;
    }
    __syncthreads();

    // epilogue: y = (y + D*xc) * silu(z), store bf16
    {
      int dloc = t & 15, i0 = t >> 4;
      #pragma unroll
      for (int rr = 0; rr < 4; rr++) {
        int i = i0 + rr * 16;
        size_t row = (size_t)b * LL + l0 + i;
        float y   = sY[i * 16 + dloc];
        float xcv = xc[row * DI + ch0 + dloc];
        float zv  = xz[row * (2 * DI) + DI + ch0 + dloc];
        float val = (y + Dv * xcv) * (zv / (1.f + __expf(-zv)));
        ypbf[row * DI + ch0 + dloc] = __float2bfloat16(val);
      }
    }
    __syncthreads();
  }
}

extern "C" void kernel_launch(void* const* d_in, const int* in_sizes, int n_in,
                              void* d_out, int out_size, void* d_ws, size_t ws_size,
                              hipStream_t stream) {
  const float* x      = (const float*)d_in[0];
  const float* W_in   = (const float*)d_in[1];
  const float* W_conv = (const float*)d_in[2];
  const float* W_x    = (const float*)d_in[3];
  const float* W_dt   = (const float*)d_in[4];
  const float* b_dt   = (const float*)d_in[5];
  const float* A_log  = (const float*)d_in[6];
  const float* Dp     = (const float*)d_in[7];
  const float* W_out  = (const float*)d_in[8];
  float* out = (float*)d_out;

  char* ws = (char*)d_ws;
  // workspace layout (bytes)
  float*          xz     = (float*)(ws + 0);                         // 4096*3072*4 = 50331648
  __hip_bfloat16* xbf    = (__hip_bfloat16*)(ws + 50331648);         // 4096*768*2  =  6291456
  __hip_bfloat16* Winbf  = (__hip_bfloat16*)(ws + 56623104);         // 3072*768*2  =  4718592
  float*          xc     = (float*)(ws + 61341696);                  // 4096*1536*4 = 25165824
  __hip_bfloat16* xcbf   = (__hip_bfloat16*)(ws + 86507520);         // 4096*1536*2 = 12582912
  __hip_bfloat16* Wdtbf  = (__hip_bfloat16*)(ws + 99090432);         // 1536*1536*2 =  4718592
  float*          delta  = (float*)(ws + 103809024);                 // 4096*1536*4 = 25165824
  float*          xdbl   = (float*)(ws + 128974848);                 // 4096*32*4   =   524288
  __hip_bfloat16* ypbf   = (__hip_bfloat16*)(ws + 129499136);        // 4096*1536*2 = 12582912
  __hip_bfloat16* Woutbf = (__hip_bfloat16*)(ws + 142082048);        // 768*1536*2  =  2359296
  // total 144441344 bytes

  // fp32 -> bf16 converts
  cvt4_k<<<(786432 + 255) / 256, 256, 0, stream>>>(x, xbf, 786432);        // 4096*768/4
  cvt4_k<<<(589824 + 255) / 256, 256, 0, stream>>>(W_in, Winbf, 589824);   // 3072*768/4
  cvt4_k<<<(589824 + 255) / 256, 256, 0, stream>>>(W_dt, Wdtbf, 589824);   // 1536*1536/4
  cvt4_k<<<(294912 + 255) / 256, 256, 0, stream>>>(W_out, Woutbf, 294912); // 768*1536/4

  // xz = x @ W_in.T   (4096 x 3072, K=768)
  {
    dim3 g(3072 / 64, 4096 / 64);
    gemm_nt<0><<<g, 256, 0, stream>>>(xbf, Winbf, xz, nullptr, MM, 2 * DI, DM);
  }
  // xc = silu(causal_dwconv(x_part))
  conv_silu_k<<<(MM * DI + 255) / 256, 256, 0, stream>>>(xz, W_conv, xc, xcbf);
  // x_dbl = xc @ W_x.T   (4096 x 32, K=1536)
  xdbl_k<<<MM, 256, 0, stream>>>(xc, W_x, xdbl);
  // delta = softplus(xc @ W_dt.T + b_dt)   (4096 x 1536, K=1536)
  {
    dim3 g(1536 / 64, 4096 / 64);
    gemm_nt<1><<<g, 256, 0, stream>>>(xcbf, Wdtbf, delta, b_dt, MM, DI, DI);
  }
  // selective scan + gating, bf16 out
  scan_k<<<BB * (DI / 16), 256, 0, stream>>>(delta, xdbl, A_log, Dp, xc, xz, ypbf);
  // out = y @ W_out.T   (4096 x 768, K=1536)
  {
    dim3 g(768 / 64, 4096 / 64);
    gemm_nt<0><<<g, 256, 0, stream>>>(ypbf, Woutbf, out, nullptr, MM, DM, DI);
  }
}

// Round 2
// 500.003 us; speedup vs baseline: 1.6991x; 1.6991x over previous
//
#include <hip/hip_runtime.h>
#include <hip/hip_bf16.h>

// Problem constants (B=2, L=2048, Dm=768, di=1536, ds=16, dc=4)
#define BB 2
#define LL 2048
#define DM 768
#define DI 1536
#define DS 16
#define MM (BB*LL)   // 4096 rows
#define NCH 32       // scan chunks
#define CHL 64       // steps per chunk
#define SEQS (BB*DI*DS)  // 49152 independent scalar recurrences

typedef short bf16x8 __attribute__((ext_vector_type(8)));
typedef float f32x4  __attribute__((ext_vector_type(4)));

__device__ __forceinline__ void gl_lds16(const void* g, void* l) {
  __builtin_amdgcn_global_load_lds((const __attribute__((address_space(1))) void*)g,
                                   (__attribute__((address_space(3))) void*)l, 16, 0, 0);
}

// ---------------- fp32 -> bf16 convert (4 elems/thread) ----------------
struct bf4 { __hip_bfloat16 a, b, c, d; };
__global__ void cvt4_k(const float* __restrict__ in, __hip_bfloat16* __restrict__ out, int n4) {
  int i = blockIdx.x * 256 + threadIdx.x;
  if (i < n4) {
    float4 v = ((const float4*)in)[i];
    bf4 o = { __float2bfloat16(v.x), __float2bfloat16(v.y),
              __float2bfloat16(v.z), __float2bfloat16(v.w) };
    ((bf4*)out)[i] = o;
  }
}

// ---------------- NT bf16 MFMA GEMM: C[M,N] = A[M,K] * W[N,K]^T ----------------
// 64x64 tile / block of 256 threads (4 waves, 2x2), BK=32, single-buffered LDS.
// EPI: 0 = plain fp32 store (stride N); 1 = +bias then softplus (stride N);
//      2 = split store: cols < DI -> C (stride DI), cols >= DI -> C2 (stride DI)
template<int EPI>
__global__ __launch_bounds__(256) void gemm_nt(const __hip_bfloat16* __restrict__ A,
                                               const __hip_bfloat16* __restrict__ W,
                                               float* __restrict__ C,
                                               float* __restrict__ C2,
                                               const float* __restrict__ bias,
                                               int M, int N, int K) {
  __shared__ short sA[2048];   // 64 rows x 32 k bf16 (frag-major)
  __shared__ short sB[2048];
  const int t = threadIdx.x;
  const int m0 = blockIdx.y * 64, n0 = blockIdx.x * 64;
  const int w = t >> 6, lane = t & 63;
  const int wm = (w >> 1) * 32, wn = (w & 1) * 32;

  f32x4 acc[2][2] = {};

  const int srow  = ((t >> 6) << 4) | (t & 15);
  const int skoff = ((t >> 4) & 3) * 8;
  const __hip_bfloat16* gA = A + (size_t)(m0 + srow) * K + skoff;
  const __hip_bfloat16* gB = W + (size_t)(n0 + srow) * K + skoff;
  short* ldsAw = sA + (w << 9);
  short* ldsBw = sB + (w << 9);
  const bf16x8* fA = (const bf16x8*)sA;
  const bf16x8* fB = (const bf16x8*)sB;
  const int ga = wm >> 4, gb = wn >> 4;

  for (int k0 = 0; k0 < K; k0 += 32) {
    gl_lds16(gA + k0, ldsAw);
    gl_lds16(gB + k0, ldsBw);
    __syncthreads();
    bf16x8 a0 = fA[(ga + 0) * 64 + lane];
    bf16x8 a1 = fA[(ga + 1) * 64 + lane];
    bf16x8 b0 = fB[(gb + 0) * 64 + lane];
    bf16x8 b1 = fB[(gb + 1) * 64 + lane];
    acc[0][0] = __builtin_amdgcn_mfma_f32_16x16x32_bf16(a0, b0, acc[0][0], 0, 0, 0);
    acc[0][1] = __builtin_amdgcn_mfma_f32_16x16x32_bf16(a0, b1, acc[0][1], 0, 0, 0);
    acc[1][0] = __builtin_amdgcn_mfma_f32_16x16x32_bf16(a1, b0, acc[1][0], 0, 0, 0);
    acc[1][1] = __builtin_amdgcn_mfma_f32_16x16x32_bf16(a1, b1, acc[1][1], 0, 0, 0);
    __syncthreads();
  }

  const int q = lane >> 4, mm = lane & 15;
  #pragma unroll
  for (int i = 0; i < 2; i++)
    #pragma unroll
    for (int j = 0; j < 2; j++) {
      int r0  = m0 + wm + i * 16 + q * 4;
      int col = n0 + wn + j * 16 + mm;
      float bv = (EPI == 1) ? bias[col] : 0.f;
      #pragma unroll
      for (int r = 0; r < 4; r++) {
        float v = acc[i][j][r];
        if (EPI == 1) { v += bv; v = (v > 20.f) ? v : log1pf(__expf(v)); }
        if (EPI == 2) {
          if (n0 < DI) C [(size_t)(r0 + r) * DI + col]        = v;
          else         C2[(size_t)(r0 + r) * DI + (col - DI)] = v;
        } else {
          C[(size_t)(r0 + r) * N + col] = v;
        }
      }
    }
}

// ---------------- depthwise causal conv (dc=4) + SiLU; writes fp32 + bf16 ----------------
// xpart layout: [MM, DI]
__global__ __launch_bounds__(256) void conv_silu_k(const float* __restrict__ xpart,
                                                   const float* __restrict__ Wc,
                                                   float* __restrict__ xc,
                                                   __hip_bfloat16* __restrict__ xcbf) {
  int idx = blockIdx.x * 256 + threadIdx.x;
  if (idx >= MM * DI) return;
  int d = idx % DI;
  int r = idx / DI;
  int l = r & (LL - 1);
  float4 wv = ((const float4*)Wc)[d];  // W_conv[d, 0, 0..3]
  const float* xp = xpart + (size_t)r * DI + d;
  float acc = wv.w * xp[0];
  if (l >= 1) acc += wv.z * xp[-(ptrdiff_t)DI];
  if (l >= 2) acc += wv.y * xp[-(ptrdiff_t)(2 * DI)];
  if (l >= 3) acc += wv.x * xp[-(ptrdiff_t)(3 * DI)];
  float s = acc / (1.f + __expf(-acc));   // silu
  xc[idx] = s;
  xcbf[idx] = __float2bfloat16(s);
}

// ---------------- x_dbl = xc @ W_x.T  (N=32, K=1536), one row per block ----------------
__global__ __launch_bounds__(256) void xdbl_k(const float* __restrict__ xc,
                                              const float* __restrict__ Wx,
                                              float* __restrict__ xd) {
  __shared__ float row[DI];
  __shared__ float red[256];
  const int m = blockIdx.x, t = threadIdx.x;
  for (int i = t; i < DI; i += 256) row[i] = xc[(size_t)m * DI + i];
  __syncthreads();
  const int n = t & 31, rr = t >> 5;
  const float4* w4 = (const float4*)(Wx + (size_t)n * DI + rr * 192);
  const float4* r4 = (const float4*)(row + rr * 192);
  float ss = 0.f;
  #pragma unroll 8
  for (int k = 0; k < 48; k++) {
    float4 a = r4[k], b = w4[k];
    ss += a.x * b.x + a.y * b.y + a.z * b.z + a.w * b.w;
  }
  red[t] = ss;
  __syncthreads();
  if (t < 32) {
    float tot = 0.f;
    #pragma unroll
    for (int r2 = 0; r2 < 8; r2++) tot += red[r2 * 32 + t];
    xd[(size_t)m * 32 + t] = tot;
  }
}

// ================= chunked selective scan =================
// Pass 1: per (b, d, chunk): local scan of 64 steps with h=0; 16 states in
// registers (pure ILP, no cross-lane). Writes prodA, hend at
// [chunk][ (b*DI+d)*16 + s ].
__global__ __launch_bounds__(64) void scan_part_k(const float* __restrict__ delta,
                                                  const float* __restrict__ xdbl,
                                                  const float* __restrict__ A_log,
                                                  float* __restrict__ prodA,
                                                  float* __restrict__ hend) {
  __shared__ float sBC[CHL * 32];
  const int t = threadIdx.x;
  const int dg = blockIdx.x % (DI / 64);
  const int chunk = (blockIdx.x / (DI / 64)) % NCH;
  const int b = blockIdx.x / ((DI / 64) * NCH);
  const int d = dg * 64 + t;

  float a[16];
  #pragma unroll
  for (int s = 0; s < 16; s++) a[s] = -__expf(A_log[s]);

  const float4* src = (const float4*)(xdbl + ((size_t)b * LL + chunk * CHL) * 32);
  #pragma unroll
  for (int k = 0; k < 8; k++) ((float4*)sBC)[t + k * 64] = src[t + k * 64];
  __syncthreads();

  float h[16], p[16];
  #pragma unroll
  for (int s = 0; s < 16; s++) { h[s] = 0.f; p[s] = 1.f; }

  const float* dptr = delta + ((size_t)b * LL + chunk * CHL) * DI + d;
  #pragma unroll 2
  for (int i = 0; i < CHL; i++) {
    float dlt = dptr[(size_t)i * DI];
    const float4* bc = (const float4*)(sBC + i * 32);
    float4 B0 = bc[0], B1 = bc[1], B2 = bc[2], B3 = bc[3];
    float Bv[16] = {B0.x,B0.y,B0.z,B0.w, B1.x,B1.y,B1.z,B1.w,
                    B2.x,B2.y,B2.z,B2.w, B3.x,B3.y,B3.z,B3.w};
    #pragma unroll
    for (int s = 0; s < 16; s++) {
      float dA = __expf(dlt * a[s]);
      h[s] = dA * h[s] + dlt * Bv[s];
      p[s] *= dA;
    }
  }
  size_t o = (size_t)chunk * SEQS + ((size_t)b * DI + d) * 16;
  #pragma unroll
  for (int s = 0; s < 16; s += 4) {
    ((float4*)(prodA + o))[s >> 2] = make_float4(p[s], p[s+1], p[s+2], p[s+3]);
    ((float4*)(hend  + o))[s >> 2] = make_float4(h[s], h[s+1], h[s+2], h[s+3]);
  }
}

// Pass 2: combine 32 chunks per sequence. hstart[c] = running state before chunk c.
__global__ __launch_bounds__(64) void scan_comb_k(const float* __restrict__ prodA,
                                                  const float* __restrict__ hend,
                                                  float* __restrict__ hstart) {
  int idx = blockIdx.x * 64 + threadIdx.x;   // 0 .. SEQS-1
  float run = 0.f;
  #pragma unroll
  for (int c = 0; c < NCH; c++) {
    size_t o = (size_t)c * SEQS + idx;
    hstart[o] = run;
    run = prodA[o] * run + hend[o];
  }
}

// Pass 3: re-scan each chunk from its true h_start, produce
// y = (sum_s h*C + D*xc) * silu(z), bf16 out.
__global__ __launch_bounds__(64) void scan_fin_k(const float* __restrict__ delta,
                                                 const float* __restrict__ xdbl,
                                                 const float* __restrict__ A_log,
                                                 const float* __restrict__ Dp,
                                                 const float* __restrict__ xc,
                                                 const float* __restrict__ z,
                                                 const float* __restrict__ hstart,
                                                 __hip_bfloat16* __restrict__ ypbf) {
  __shared__ float sBC[CHL * 32];
  const int t = threadIdx.x;
  const int dg = blockIdx.x % (DI / 64);
  const int chunk = (blockIdx.x / (DI / 64)) % NCH;
  const int b = blockIdx.x / ((DI / 64) * NCH);
  const int d = dg * 64 + t;

  float a[16];
  #pragma unroll
  for (int s = 0; s < 16; s++) a[s] = -__expf(A_log[s]);

  const float4* src = (const float4*)(xdbl + ((size_t)b * LL + chunk * CHL) * 32);
  #pragma unroll
  for (int k = 0; k < 8; k++) ((float4*)sBC)[t + k * 64] = src[t + k * 64];
  __syncthreads();

  float h[16];
  size_t o = (size_t)chunk * SEQS + ((size_t)b * DI + d) * 16;
  #pragma unroll
  for (int s = 0; s < 16; s += 4) {
    float4 v = ((const float4*)(hstart + o))[s >> 2];
    h[s] = v.x; h[s+1] = v.y; h[s+2] = v.z; h[s+3] = v.w;
  }
  const float Dv = Dp[d];

  const size_t rbase = (size_t)b * LL + chunk * CHL;
  const float* dptr = delta + rbase * DI + d;
  const float* xcp  = xc    + rbase * DI + d;
  const float* zp   = z     + rbase * DI + d;
  __hip_bfloat16* yp = ypbf + rbase * DI + d;

  #pragma unroll 2
  for (int i = 0; i < CHL; i++) {
    float dlt = dptr[(size_t)i * DI];
    const float4* bc = (const float4*)(sBC + i * 32);
    float4 B0 = bc[0], B1 = bc[1], B2 = bc[2], B3 = bc[3];
    float4 C0 = bc[4], C1 = bc[5], C2 = bc[6], C3 = bc[7];
    float Bv[16] = {B0.x,B0.y,B0.z,B0.w, B1.x,B1.y,B1.z,B1.w,
                    B2.x,B2.y,B2.z,B2.w, B3.x,B3.y,B3.z,B3.w};
    float Cv[16] = {C0.x,C0.y,C0.z,C0.w, C1.x,C1.y,C1.z,C1.w,
                    C2.x,C2.y,C2.z,C2.w, C3.x,C3.y,C3.z,C3.w};
    float y = 0.f;
    #pragma unroll
    for (int s = 0; s < 16; s++) {
      float dA = __expf(dlt * a[s]);
      h[s] = dA * h[s] + dlt * Bv[s];
      y += h[s] * Cv[s];
    }
    float xcv = xcp[(size_t)i * DI];
    float zv  = zp [(size_t)i * DI];
    float val = (y + Dv * xcv) * (zv / (1.f + __expf(-zv)));
    yp[(size_t)i * DI] = __float2bfloat16(val);
  }
}

extern "C" void kernel_launch(void* const* d_in, const int* in_sizes, int n_in,
                              void* d_out, int out_size, void* d_ws, size_t ws_size,
                              hipStream_t stream) {
  const float* x      = (const float*)d_in[0];
  const float* W_in   = (const float*)d_in[1];
  const float* W_conv = (const float*)d_in[2];
  const float* W_x    = (const float*)d_in[3];
  const float* W_dt   = (const float*)d_in[4];
  const float* b_dt   = (const float*)d_in[5];
  const float* A_log  = (const float*)d_in[6];
  const float* Dp     = (const float*)d_in[7];
  const float* W_out  = (const float*)d_in[8];
  float* out = (float*)d_out;

  char* ws = (char*)d_ws;
  // workspace layout (bytes), total 144441344
  float*          xpart  = (float*)(ws + 0);                         // 4096*1536*4 = 25165824
  float*          z      = (float*)(ws + 25165824);                  // 4096*1536*4 = 25165824
  __hip_bfloat16* xbf    = (__hip_bfloat16*)(ws + 50331648);         // 4096*768*2  =  6291456
  __hip_bfloat16* Winbf  = (__hip_bfloat16*)(ws + 56623104);         // 3072*768*2  =  4718592
  float*          xc     = (float*)(ws + 61341696);                  // 4096*1536*4 = 25165824
  __hip_bfloat16* xcbf   = (__hip_bfloat16*)(ws + 86507520);         // 4096*1536*2 = 12582912
  __hip_bfloat16* Wdtbf  = (__hip_bfloat16*)(ws + 99090432);         // 1536*1536*2 =  4718592
  float*          delta  = (float*)(ws + 103809024);                 // 4096*1536*4 = 25165824
  float*          xdbl   = (float*)(ws + 128974848);                 // 4096*32*4   =   524288
  __hip_bfloat16* ypbf   = (__hip_bfloat16*)(ws + 129499136);        // 4096*1536*2 = 12582912
  __hip_bfloat16* Woutbf = (__hip_bfloat16*)(ws + 142082048);        // 768*1536*2  =  2359296
  // scan intermediates alias xpart's region (dead after conv_silu_k):
  float*          prodA  = (float*)(ws + 0);                         // 32*49152*4 = 6291456
  float*          hend   = (float*)(ws + 6291456);                   // 6291456
  float*          hstart = (float*)(ws + 12582912);                  // 6291456

  // fp32 -> bf16 converts
  cvt4_k<<<(786432 + 255) / 256, 256, 0, stream>>>(x, xbf, 786432);
  cvt4_k<<<(589824 + 255) / 256, 256, 0, stream>>>(W_in, Winbf, 589824);
  cvt4_k<<<(589824 + 255) / 256, 256, 0, stream>>>(W_dt, Wdtbf, 589824);
  cvt4_k<<<(294912 + 255) / 256, 256, 0, stream>>>(W_out, Woutbf, 294912);

  // xz = x @ W_in.T (4096 x 3072, K=768), split-stored into xpart | z
  {
    dim3 g(3072 / 64, 4096 / 64);
    gemm_nt<2><<<g, 256, 0, stream>>>(xbf, Winbf, xpart, z, nullptr, MM, 2 * DI, DM);
  }
  // xc = silu(causal_dwconv(xpart))
  conv_silu_k<<<(MM * DI + 255) / 256, 256, 0, stream>>>(xpart, W_conv, xc, xcbf);
  // x_dbl = xc @ W_x.T (4096 x 32, K=1536)
  xdbl_k<<<MM, 256, 0, stream>>>(xc, W_x, xdbl);
  // delta = softplus(xc @ W_dt.T + b_dt) (4096 x 1536, K=1536)
  {
    dim3 g(1536 / 64, 4096 / 64);
    gemm_nt<1><<<g, 256, 0, stream>>>(xcbf, Wdtbf, delta, nullptr, b_dt, MM, DI, DI);
  }
  // chunked selective scan + gating
  scan_part_k<<<BB * NCH * (DI / 64), 64, 0, stream>>>(delta, xdbl, A_log, prodA, hend);
  scan_comb_k<<<SEQS / 64, 64, 0, stream>>>(prodA, hend, hstart);
  scan_fin_k<<<BB * NCH * (DI / 64), 64, 0, stream>>>(delta, xdbl, A_log, Dp, xc, z,
                                                      hstart, ypbf);
  // out = y @ W_out.T (4096 x 768, K=1536)
  {
    dim3 g(768 / 64, 4096 / 64);
    gemm_nt<0><<<g, 256, 0, stream>>>(ypbf, Woutbf, out, nullptr, nullptr, MM, DM, DI);
  }
}

// Round 3
// 394.207 us; speedup vs baseline: 2.1551x; 1.2684x over previous
//
#include <hip/hip_runtime.h>
#include <hip/hip_bf16.h>

// Problem constants (B=2, L=2048, Dm=768, di=1536, ds=16, dc=4)
#define BB 2
#define LL 2048
#define DM 768
#define DI 1536
#define DS 16
#define MM (BB*LL)   // 4096 rows
#define NCH 32       // scan chunks
#define CHL 64       // steps per chunk
#define SEQS (BB*DI*DS)  // 49152 independent scalar recurrences
#define NC2 1664     // delta GEMM fused N: 1536 (W_dt) + 32 (W_x) + 96 pad = 13*128

typedef short bf16x8 __attribute__((ext_vector_type(8)));
typedef float f32x4  __attribute__((ext_vector_type(4)));

__device__ __forceinline__ void gl_lds16(const void* g, void* l) {
  __builtin_amdgcn_global_load_lds((const __attribute__((address_space(1))) void*)g,
                                   (__attribute__((address_space(3))) void*)l, 16, 0, 0);
}

// ---------------- fp32 -> bf16 convert (4 elems/thread) ----------------
struct bf4 { __hip_bfloat16 a, b, c, d; };
__global__ void cvt4_k(const float* __restrict__ in, __hip_bfloat16* __restrict__ out, int n4) {
  int i = blockIdx.x * 256 + threadIdx.x;
  if (i < n4) {
    float4 v = ((const float4*)in)[i];
    bf4 o = { __float2bfloat16(v.x), __float2bfloat16(v.y),
              __float2bfloat16(v.z), __float2bfloat16(v.w) };
    ((bf4*)out)[i] = o;
  }
}

// ---------------- build Wcomb[1664][1536] bf16 = [W_dt ; W_x ; 0-pad] ----------------
__global__ void wcomb_k(const float* __restrict__ Wdt, const float* __restrict__ Wx,
                        __hip_bfloat16* __restrict__ out) {
  int i = blockIdx.x * 256 + threadIdx.x;          // one float4 per thread
  if (i >= NC2 * DI / 4) return;
  int e = i * 4;
  int row = e / DI, colb = e % DI;
  float4 v;
  if (row < DI)            v = ((const float4*)Wdt)[i];
  else if (row < DI + 32)  v = *(const float4*)(Wx + (size_t)(row - DI) * DI + colb);
  else                     v = make_float4(0.f, 0.f, 0.f, 0.f);
  bf4 o = { __float2bfloat16(v.x), __float2bfloat16(v.y),
            __float2bfloat16(v.z), __float2bfloat16(v.w) };
  ((bf4*)out)[i] = o;
}

// ---------------- NT bf16 MFMA GEMM, 128x128 tile (m97 structure) ----------------
// C[M,N] = A[M,K] * W[N,K]^T. 256 threads = 4 waves in 2x2, each wave 64x64 via
// 4x4 grid of 16x16x32 MFMA. BK=32, frag-major LDS via global_load_lds width=16.
// EPI: 0 = plain fp32 store (stride N)
//      2 = split: col<DI -> C (stride DI), else -> C2 (stride DI)   [xz GEMM]
//      3 = col<DI -> softplus(v+bias[col]) -> C (stride DI);
//          col in [DI,DI+32) -> C2 (stride 32); else discard        [delta+xdbl]
template<int EPI>
__global__ __launch_bounds__(256) void gemm128(const __hip_bfloat16* __restrict__ A,
                                               const __hip_bfloat16* __restrict__ W,
                                               float* __restrict__ C,
                                               float* __restrict__ C2,
                                               const float* __restrict__ bias,
                                               int M, int N, int K) {
  __shared__ short sA[128 * 32];   // 8192 B, frag-major: 8 blocks of 16 rows
  __shared__ short sB[128 * 32];
  const int t = threadIdx.x;
  const int m0 = blockIdx.y * 128, n0 = blockIdx.x * 128;
  const int w = t >> 6, lane = t & 63;
  const int wm = (w >> 1) * 64, wn = (w & 1) * 64;

  f32x4 acc[4][4] = {};

  // staging: wave w stages A row-blocks {w, w+4} and B row-blocks {w, w+4}
  const int srow  = lane & 15;          // row within 16-row block
  const int skoff = (lane >> 4) * 8;    // k-chunk
  const __hip_bfloat16* gA0 = A + (size_t)(m0 + w * 16 + srow) * K + skoff;
  const __hip_bfloat16* gA1 = gA0 + (size_t)64 * K;
  const __hip_bfloat16* gB0 = W + (size_t)(n0 + w * 16 + srow) * K + skoff;
  const __hip_bfloat16* gB1 = gB0 + (size_t)64 * K;
  short* ldsA0 = sA + (w)     * 512;    // 512 shorts = 1024 B per 16-row block
  short* ldsA1 = sA + (w + 4) * 512;
  short* ldsB0 = sB + (w)     * 512;
  short* ldsB1 = sB + (w + 4) * 512;
  const bf16x8* fA = (const bf16x8*)sA;
  const bf16x8* fB = (const bf16x8*)sB;
  const int ga = wm >> 4, gb = wn >> 4;

  for (int k0 = 0; k0 < K; k0 += 32) {
    gl_lds16(gA0 + k0, ldsA0);
    gl_lds16(gA1 + k0, ldsA1);
    gl_lds16(gB0 + k0, ldsB0);
    gl_lds16(gB1 + k0, ldsB1);
    __syncthreads();
    bf16x8 af[4], bfr[4];
    #pragma unroll
    for (int i = 0; i < 4; i++) af[i]  = fA[(ga + i) * 64 + lane];
    #pragma unroll
    for (int j = 0; j < 4; j++) bfr[j] = fB[(gb + j) * 64 + lane];
    #pragma unroll
    for (int i = 0; i < 4; i++)
      #pragma unroll
      for (int j = 0; j < 4; j++)
        acc[i][j] = __builtin_amdgcn_mfma_f32_16x16x32_bf16(af[i], bfr[j], acc[i][j], 0, 0, 0);
    __syncthreads();
  }

  const int q = lane >> 4, mm = lane & 15;
  #pragma unroll
  for (int i = 0; i < 4; i++)
    #pragma unroll
    for (int j = 0; j < 4; j++) {
      int r0  = m0 + wm + i * 16 + q * 4;
      int col = n0 + wn + j * 16 + mm;
      #pragma unroll
      for (int r = 0; r < 4; r++) {
        float v = acc[i][j][r];
        if (EPI == 0) {
          C[(size_t)(r0 + r) * N + col] = v;
        } else if (EPI == 2) {
          if (col < DI) C [(size_t)(r0 + r) * DI + col]        = v;
          else          C2[(size_t)(r0 + r) * DI + (col - DI)] = v;
        } else {  // EPI == 3
          if (col < DI) {
            float vv = v + bias[col];
            vv = (vv > 20.f) ? vv : log1pf(__expf(vv));
            C[(size_t)(r0 + r) * DI + col] = vv;
          } else if (col < DI + 32) {
            C2[(size_t)(r0 + r) * 32 + (col - DI)] = v;
          }
        }
      }
    }
}

// ---------------- depthwise causal conv (dc=4) + SiLU; writes fp32 + bf16 ----------------
__global__ __launch_bounds__(256) void conv_silu_k(const float* __restrict__ xpart,
                                                   const float* __restrict__ Wc,
                                                   float* __restrict__ xc,
                                                   __hip_bfloat16* __restrict__ xcbf) {
  int idx = blockIdx.x * 256 + threadIdx.x;
  if (idx >= MM * DI) return;
  int d = idx % DI;
  int r = idx / DI;
  int l = r & (LL - 1);
  float4 wv = ((const float4*)Wc)[d];  // W_conv[d, 0, 0..3]
  const float* xp = xpart + (size_t)r * DI + d;
  float acc = wv.w * xp[0];
  if (l >= 1) acc += wv.z * xp[-(ptrdiff_t)DI];
  if (l >= 2) acc += wv.y * xp[-(ptrdiff_t)(2 * DI)];
  if (l >= 3) acc += wv.x * xp[-(ptrdiff_t)(3 * DI)];
  float s = acc / (1.f + __expf(-acc));   // silu
  xc[idx] = s;
  xcbf[idx] = __float2bfloat16(s);
}

// ================= chunked selective scan =================
__global__ __launch_bounds__(64) void scan_part_k(const float* __restrict__ delta,
                                                  const float* __restrict__ xdbl,
                                                  const float* __restrict__ A_log,
                                                  float* __restrict__ prodA,
                                                  float* __restrict__ hend) {
  __shared__ float sBC[CHL * 32];
  const int t = threadIdx.x;
  const int dg = blockIdx.x % (DI / 64);
  const int chunk = (blockIdx.x / (DI / 64)) % NCH;
  const int b = blockIdx.x / ((DI / 64) * NCH);
  const int d = dg * 64 + t;

  float a[16];
  #pragma unroll
  for (int s = 0; s < 16; s++) a[s] = -__expf(A_log[s]);

  const float4* src = (const float4*)(xdbl + ((size_t)b * LL + chunk * CHL) * 32);
  #pragma unroll
  for (int k = 0; k < 8; k++) ((float4*)sBC)[t + k * 64] = src[t + k * 64];
  __syncthreads();

  float h[16], p[16];
  #pragma unroll
  for (int s = 0; s < 16; s++) { h[s] = 0.f; p[s] = 1.f; }

  const float* dptr = delta + ((size_t)b * LL + chunk * CHL) * DI + d;
  #pragma unroll 2
  for (int i = 0; i < CHL; i++) {
    float dlt = dptr[(size_t)i * DI];
    const float4* bc = (const float4*)(sBC + i * 32);
    float4 B0 = bc[0], B1 = bc[1], B2 = bc[2], B3 = bc[3];
    float Bv[16] = {B0.x,B0.y,B0.z,B0.w, B1.x,B1.y,B1.z,B1.w,
                    B2.x,B2.y,B2.z,B2.w, B3.x,B3.y,B3.z,B3.w};
    #pragma unroll
    for (int s = 0; s < 16; s++) {
      float dA = __expf(dlt * a[s]);
      h[s] = dA * h[s] + dlt * Bv[s];
      p[s] *= dA;
    }
  }
  size_t o = (size_t)chunk * SEQS + ((size_t)b * DI + d) * 16;
  #pragma unroll
  for (int s = 0; s < 16; s += 4) {
    ((float4*)(prodA + o))[s >> 2] = make_float4(p[s], p[s+1], p[s+2], p[s+3]);
    ((float4*)(hend  + o))[s >> 2] = make_float4(h[s], h[s+1], h[s+2], h[s+3]);
  }
}

__global__ __launch_bounds__(64) void scan_comb_k(const float* __restrict__ prodA,
                                                  const float* __restrict__ hend,
                                                  float* __restrict__ hstart) {
  int idx = blockIdx.x * 64 + threadIdx.x;   // 0 .. SEQS-1
  float run = 0.f;
  #pragma unroll
  for (int c = 0; c < NCH; c++) {
    size_t o = (size_t)c * SEQS + idx;
    hstart[o] = run;
    run = prodA[o] * run + hend[o];
  }
}

__global__ __launch_bounds__(64) void scan_fin_k(const float* __restrict__ delta,
                                                 const float* __restrict__ xdbl,
                                                 const float* __restrict__ A_log,
                                                 const float* __restrict__ Dp,
                                                 const float* __restrict__ xc,
                                                 const float* __restrict__ z,
                                                 const float* __restrict__ hstart,
                                                 __hip_bfloat16* __restrict__ ypbf) {
  __shared__ float sBC[CHL * 32];
  const int t = threadIdx.x;
  const int dg = blockIdx.x % (DI / 64);
  const int chunk = (blockIdx.x / (DI / 64)) % NCH;
  const int b = blockIdx.x / ((DI / 64) * NCH);
  const int d = dg * 64 + t;

  float a[16];
  #pragma unroll
  for (int s = 0; s < 16; s++) a[s] = -__expf(A_log[s]);

  const float4* src = (const float4*)(xdbl + ((size_t)b * LL + chunk * CHL) * 32);
  #pragma unroll
  for (int k = 0; k < 8; k++) ((float4*)sBC)[t + k * 64] = src[t + k * 64];
  __syncthreads();

  float h[16];
  size_t o = (size_t)chunk * SEQS + ((size_t)b * DI + d) * 16;
  #pragma unroll
  for (int s = 0; s < 16; s += 4) {
    float4 v = ((const float4*)(hstart + o))[s >> 2];
    h[s] = v.x; h[s+1] = v.y; h[s+2] = v.z; h[s+3] = v.w;
  }
  const float Dv = Dp[d];

  const size_t rbase = (size_t)b * LL + chunk * CHL;
  const float* dptr = delta + rbase * DI + d;
  const float* xcp  = xc    + rbase * DI + d;
  const float* zp   = z     + rbase * DI + d;
  __hip_bfloat16* yp = ypbf + rbase * DI + d;

  #pragma unroll 2
  for (int i = 0; i < CHL; i++) {
    float dlt = dptr[(size_t)i * DI];
    const float4* bc = (const float4*)(sBC + i * 32);
    float4 B0 = bc[0], B1 = bc[1], B2 = bc[2], B3 = bc[3];
    float4 C0 = bc[4], C1 = bc[5], C2 = bc[6], C3 = bc[7];
    float Bv[16] = {B0.x,B0.y,B0.z,B0.w, B1.x,B1.y,B1.z,B1.w,
                    B2.x,B2.y,B2.z,B2.w, B3.x,B3.y,B3.z,B3.w};
    float Cv[16] = {C0.x,C0.y,C0.z,C0.w, C1.x,C1.y,C1.z,C1.w,
                    C2.x,C2.y,C2.z,C2.w, C3.x,C3.y,C3.z,C3.w};
    float y = 0.f;
    #pragma unroll
    for (int s = 0; s < 16; s++) {
      float dA = __expf(dlt * a[s]);
      h[s] = dA * h[s] + dlt * Bv[s];
      y += h[s] * Cv[s];
    }
    float xcv = xcp[(size_t)i * DI];
    float zv  = zp [(size_t)i * DI];
    float val = (y + Dv * xcv) * (zv / (1.f + __expf(-zv)));
    yp[(size_t)i * DI] = __float2bfloat16(val);
  }
}

extern "C" void kernel_launch(void* const* d_in, const int* in_sizes, int n_in,
                              void* d_out, int out_size, void* d_ws, size_t ws_size,
                              hipStream_t stream) {
  const float* x      = (const float*)d_in[0];
  const float* W_in   = (const float*)d_in[1];
  const float* W_conv = (const float*)d_in[2];
  const float* W_x    = (const float*)d_in[3];
  const float* W_dt   = (const float*)d_in[4];
  const float* b_dt   = (const float*)d_in[5];
  const float* A_log  = (const float*)d_in[6];
  const float* Dp     = (const float*)d_in[7];
  const float* W_out  = (const float*)d_in[8];
  float* out = (float*)d_out;

  char* ws = (char*)d_ws;
  // workspace layout (bytes), total 144441344 (unchanged from round 2)
  float*          xpart  = (float*)(ws + 0);                         // 25165824
  float*          z      = (float*)(ws + 25165824);                  // 25165824
  __hip_bfloat16* xbf    = (__hip_bfloat16*)(ws + 50331648);         // 6291456 (dead after GEMM1)
  __hip_bfloat16* Winbf  = (__hip_bfloat16*)(ws + 56623104);         // 4718592
  float*          xc     = (float*)(ws + 61341696);                  // 25165824
  __hip_bfloat16* xcbf   = (__hip_bfloat16*)(ws + 86507520);         // 12582912
  float*          delta  = (float*)(ws + 103809024);                 // 25165824
  float*          xdbl   = (float*)(ws + 128974848);                 // 524288
  __hip_bfloat16* ypbf   = (__hip_bfloat16*)(ws + 129499136);        // 12582912
  __hip_bfloat16* Woutbf = (__hip_bfloat16*)(ws + 142082048);        // 2359296
  // aliases of dead regions:
  float*          prodA  = (float*)(ws + 0);                         // xpart region (dead after conv)
  float*          hend   = (float*)(ws + 6291456);
  float*          hstart = (float*)(ws + 12582912);
  __hip_bfloat16* Wcomb  = (__hip_bfloat16*)(ws + 50331648);         // xbf region: 1664*1536*2 = 5111808 <= 6291456

  // fp32 -> bf16 converts
  cvt4_k<<<(786432 + 255) / 256, 256, 0, stream>>>(x, xbf, 786432);
  cvt4_k<<<(589824 + 255) / 256, 256, 0, stream>>>(W_in, Winbf, 589824);
  cvt4_k<<<(294912 + 255) / 256, 256, 0, stream>>>(W_out, Woutbf, 294912);

  // xz = x @ W_in.T (4096 x 3072, K=768), split-stored into xpart | z
  {
    dim3 g(3072 / 128, 4096 / 128);
    gemm128<2><<<g, 256, 0, stream>>>(xbf, Winbf, xpart, z, nullptr, MM, 2 * DI, DM);
  }
  // xc = silu(causal_dwconv(xpart))
  conv_silu_k<<<(MM * DI + 255) / 256, 256, 0, stream>>>(xpart, W_conv, xc, xcbf);
  // Wcomb = [W_dt ; W_x ; 0] bf16 (aliases xbf, dead after GEMM1)
  wcomb_k<<<(NC2 * DI / 4 + 255) / 256, 256, 0, stream>>>(W_dt, W_x, Wcomb);
  // delta = softplus(xc @ W_dt.T + b_dt) AND xdbl = xc @ W_x.T, one GEMM (N=1664)
  {
    dim3 g(NC2 / 128, 4096 / 128);
    gemm128<3><<<g, 256, 0, stream>>>(xcbf, Wcomb, delta, xdbl, b_dt, MM, NC2, DI);
  }
  // chunked selective scan + gating
  scan_part_k<<<BB * NCH * (DI / 64), 64, 0, stream>>>(delta, xdbl, A_log, prodA, hend);
  scan_comb_k<<<SEQS / 64, 64, 0, stream>>>(prodA, hend, hstart);
  scan_fin_k<<<BB * NCH * (DI / 64), 64, 0, stream>>>(delta, xdbl, A_log, Dp, xc, z,
                                                      hstart, ypbf);
  // out = y @ W_out.T (4096 x 768, K=1536)
  {
    dim3 g(768 / 128, 4096 / 128);
    gemm128<0><<<g, 256, 0, stream>>>(ypbf, Woutbf, out, nullptr, nullptr, MM, DM, DI);
  }
}